// Round 7
// baseline (102.352 us; speedup 1.0000x reference)
//
#include <hip/hip_runtime.h>

// WaveKANLinear: out[n,o] = sum_d mexhat((ln(x)[n,d]-t[o,d])/s[o,d]) * ww[o,d]
//                           + silu(sum_d x[n,d]*bw[o,d])
// N=8192, D=128, O=128, float32.
// R12: R6 rejected by compiler: "+v" tied constraint on float4 (multi-reg
//      aggregate) is unsupported. Pin SCALAR components instead (supported
//      form). Design unchanged from R6:
//      (a) per-scalar asm volatile("" : "+v"(f)) pins weights after load --
//          opaque redefinition, not rematerializable (R5's failure mode:
//          VGPR_Count=84, weights re-loaded from L2 every row -> 2GB L2
//          traffic -> 40.5us L2-bound).
//      (b) 16 d per thread (16 f4 = 64 VGPR pinned), BLOCK=1024, grid=256,
//          launch_bounds(1024,4) -> 128-VGPR cap, 16 waves/CU.
//      (c) raw-x LDS stream deleted: base reconstructed exactly from ln:
//          base = isr*(A - cb_o) + mean*sb_o, A = sum ln*(bw/gamma).
//      VALU floor ~13.4us (exp2-dominated). Bench floor ~58us = one
//      unconditional ws poison fill -> prep + d_ws stay (free).

#define D_DIM 128
#define O_DIM 128
#define ROWS  32     // rows per block
#define BLOCK 1024   // 16 waves; o = wv*8 + (lane&7), dg = lane>>3 (16 d each)
#define XSTR  161    // f4 stride per dg block: 32 rows * 5 (4 f4 + 1 pad) + 1

#define C1     0.72134752f   // 0.5*log2(e); exp(-z^2/2) = exp2(-C1*z^2)
#define SQRT_C 0.84932180f   // sqrt(C1)
#define WWK    1.2023651f    // MEX_C / C1, MEX_C = 2/(sqrt(3)*pi^0.25)
#define LOG2E  1.44269504f

typedef float v2f __attribute__((ext_vector_type(2)));

#define PIN4(v) asm volatile("" : "+v"((v).x), "+v"((v).y), "+v"((v).z), "+v"((v).w))

// softplus(scale)+0.1 -> {t*is2, is2, ww*WWK, bw'}   (bw' = bw/gamma)
__device__ __forceinline__ void wk_pair(float sc, float tr, float w_w, float b_wp,
                                        float& wx, float& wy, float& wz, float& wb) {
    float sp  = fmaxf(sc, 0.0f) + __logf(1.0f + __expf(-fabsf(sc)));  // stable
    float is2 = SQRT_C / (sp + 0.1f);
    wx = tr * is2; wy = is2; wz = w_w * WWK; wb = b_wp;
}

// Prep: SoA d-pair layout. For d-pair p (d=2p,2p+1), column o:
//   ws[(p*O+o)*2+0] = {wx0,wx1,wy0,wy1}
//   ws[(p*O+o)*2+1] = {wz0,wz1,bw0/g0,bw1/g1}
__global__ __launch_bounds__(256) void wavekan_prep(
    const float* __restrict__ scale,
    const float* __restrict__ trans,
    const float* __restrict__ ww,
    const float* __restrict__ bw,
    const float* __restrict__ gamma,
    float4* __restrict__ wsW)
{
    int idx = blockIdx.x * blockDim.x + threadIdx.x;   // = o*64 + p
    if (idx >= O_DIM * (D_DIM / 2)) return;
    int o = idx >> 6;
    int p = idx & 63;
    int d0 = 2 * p;
    int i0 = o * D_DIM + d0;
    float wx0, wy0, wz0, wb0, wx1, wy1, wz1, wb1;
    wk_pair(scale[i0],     trans[i0],     ww[i0],     bw[i0]     / gamma[d0],     wx0, wy0, wz0, wb0);
    wk_pair(scale[i0 + 1], trans[i0 + 1], ww[i0 + 1], bw[i0 + 1] / gamma[d0 + 1], wx1, wy1, wz1, wb1);
    wsW[(p * O_DIM + o) * 2 + 0] = make_float4(wx0, wx1, wy0, wy1);
    wsW[(p * O_DIM + o) * 2 + 1] = make_float4(wz0, wz1, wb0, wb1);
}

template<bool USE_WS>
__global__ __launch_bounds__(BLOCK, 4) void wavekan_main(
    const float* __restrict__ x,
    const float* __restrict__ scale,
    const float* __restrict__ trans,
    const float* __restrict__ ww,
    const float* __restrict__ bw,
    const float* __restrict__ gamma,
    const float* __restrict__ beta,
    const float4* __restrict__ wsW,
    float* __restrict__ out,
    int N)
{
    // ln(x) staged once for 32 rows: [dg=8][row=32][4 f4 + 1 pad], +1 f4/dg.
    // Inner-loop reads: 8 distinct addrs/wave -> conflict-free 8-lane multicast.
    __shared__ float4 s_ln4[8 * XSTR];               // 20.6 KB
    __shared__ float2 s_stat[ROWS];                  // {mean, isr} per row

    const int tid  = threadIdx.x;
    const int lane = tid & 63;
    const int wv   = tid >> 6;                       // wave 0..15
    const int o    = wv * 8 + (lane & 7);            // output column
    const int dg   = lane >> 3;                      // d-group 0..7 (16 d each)
    const int row0 = blockIdx.x * ROWS;

    // ---- Weight regs: 8 d-pairs x 2 f4 = 64 VGPR (pinned below) ----
    float4 wA[8], wB[8];
    if (USE_WS) {
        #pragma unroll
        for (int k = 0; k < 8; ++k) {
            const int p = dg * 8 + k;
            wA[k] = wsW[(p * O_DIM + o) * 2 + 0];
            wB[k] = wsW[(p * O_DIM + o) * 2 + 1];
        }
    } else {
        #pragma unroll
        for (int k = 0; k < 8; ++k) {
            const int d0 = dg * 16 + 2 * k;
            const int i0 = o * D_DIM + d0;
            float wx0, wy0, wz0, wb0, wx1, wy1, wz1, wb1;
            wk_pair(scale[i0],     trans[i0],     ww[i0],     bw[i0]     / gamma[d0],     wx0, wy0, wz0, wb0);
            wk_pair(scale[i0 + 1], trans[i0 + 1], ww[i0 + 1], bw[i0 + 1] / gamma[d0 + 1], wx1, wy1, wz1, wb1);
            wA[k] = make_float4(wx0, wx1, wy0, wy1);
            wB[k] = make_float4(wz0, wz1, wb0, wb1);
        }
    }

    // ---- Phase 1: LN of 32 rows. 32 lanes x 4 elems per row. ----
    {
        const int r    = tid >> 5;       // local row 0..31
        const int j    = tid & 31;       // lane within row group
        const int d0j  = j * 4;
        const int grow = row0 + r;

        float4 v4 = make_float4(0.f, 0.f, 0.f, 0.f);
        if (grow < N)
            v4 = *reinterpret_cast<const float4*>(x + (size_t)grow * D_DIM + d0j);

        float sum = (v4.x + v4.y) + (v4.z + v4.w);
        float ssq = (v4.x * v4.x + v4.y * v4.y) + (v4.z * v4.z + v4.w * v4.w);
        #pragma unroll
        for (int m = 1; m < 32; m <<= 1) {   // 32-lane butterfly (aligned groups)
            sum += __shfl_xor(sum, m, 64);
            ssq += __shfl_xor(ssq, m, 64);
        }
        const float mean = sum * (1.0f / D_DIM);
        const float var  = ssq * (1.0f / D_DIM) - mean * mean;
        const float rstd = rsqrtf(var + 1e-5f);

        float4 g4 = *reinterpret_cast<const float4*>(gamma + d0j);
        float4 b4 = *reinterpret_cast<const float4*>(beta + d0j);

        s_ln4[(j >> 2) * XSTR + r * 5 + (j & 3)] =
            make_float4((v4.x - mean) * rstd * g4.x + b4.x,
                        (v4.y - mean) * rstd * g4.y + b4.y,
                        (v4.z - mean) * rstd * g4.z + b4.z,
                        (v4.w - mean) * rstd * g4.w + b4.w);
        if (j == 0)
            s_stat[r] = make_float2(mean, sqrtf(var + 1e-5f));  // isr = 1/rstd
    }

    // ---- One-time per-o constants: cb = sum beta*bw', sb = sum bw (=bw'*g) ----
    float cb = 0.f, sb = 0.f;
    #pragma unroll
    for (int k = 0; k < 8; ++k) {
        float2 bt = *reinterpret_cast<const float2*>(beta  + dg * 16 + 2 * k);
        float2 gt = *reinterpret_cast<const float2*>(gamma + dg * 16 + 2 * k);
        cb += bt.x * wB[k].z + bt.y * wB[k].w;
        sb += gt.x * wB[k].z + gt.y * wB[k].w;
    }
    cb += __shfl_xor(cb, 8, 64); cb += __shfl_xor(cb, 16, 64); cb += __shfl_xor(cb, 32, 64);
    sb += __shfl_xor(sb, 8, 64); sb += __shfl_xor(sb, 16, 64); sb += __shfl_xor(sb, 32, 64);

    // ---- Pin weights: opaque scalar redefinition -> no remat, no re-load ----
    #pragma unroll
    for (int k = 0; k < 8; ++k) {
        PIN4(wA[k]);
        PIN4(wB[k]);
    }

    __syncthreads();      // the only block-wide barrier

    // ---- Phase 2: barrier-free row sweep; weights from registers ----
    #pragma unroll 1
    for (int r = 0; r < ROWS; ++r) {
        const int xb = dg * XSTR + r * 5;
        v2f aw = {0.f, 0.f};
        v2f ab = {0.f, 0.f};
        #pragma unroll
        for (int k4 = 0; k4 < 4; ++k4) {
            float4 xl = s_ln4[xb + k4];        // 8-addr multicast, conflict-free
            float4 a0 = wA[2 * k4],     c0 = wB[2 * k4];
            float4 a1 = wA[2 * k4 + 1], c1 = wB[2 * k4 + 1];

            v2f u, qq, e;
            u  = (v2f){xl.x, xl.y} * (v2f){a0.z, a0.w} - (v2f){a0.x, a0.y};
            qq = u * u;
            e  = (v2f){__builtin_amdgcn_exp2f(-qq.x), __builtin_amdgcn_exp2f(-qq.y)};
            aw += ((qq - C1) * e) * (v2f){c0.x, c0.y};
            ab += (v2f){xl.x, xl.y} * (v2f){c0.z, c0.w};

            u  = (v2f){xl.z, xl.w} * (v2f){a1.z, a1.w} - (v2f){a1.x, a1.y};
            qq = u * u;
            e  = (v2f){__builtin_amdgcn_exp2f(-qq.x), __builtin_amdgcn_exp2f(-qq.y)};
            aw += ((qq - C1) * e) * (v2f){c1.x, c1.y};
            ab += (v2f){xl.z, xl.w} * (v2f){c1.z, c1.w};
        }
        float wav = aw.x + aw.y;
        float A   = ab.x + ab.y;
        // cross-dg reduce (dg = lane bits 3..5)
        wav += __shfl_xor(wav, 8, 64); wav += __shfl_xor(wav, 16, 64); wav += __shfl_xor(wav, 32, 64);
        A   += __shfl_xor(A,   8, 64); A   += __shfl_xor(A,   16, 64); A   += __shfl_xor(A,   32, 64);

        if (dg == 0) {
            const int grow = row0 + r;
            if (grow < N) {
                float2 st   = s_stat[r];                        // broadcast
                float  base = (A - cb) * st.y + st.x * sb;      // exact reconstr.
                float  sig  = 1.0f / (1.0f + __builtin_amdgcn_exp2f(-LOG2E * base));
                out[(size_t)grow * O_DIM + o] = wav + base * sig;
            }
        }
    }
}

extern "C" void kernel_launch(void* const* d_in, const int* in_sizes, int n_in,
                              void* d_out, int out_size, void* d_ws, size_t ws_size,
                              hipStream_t stream) {
    const float* x     = (const float*)d_in[0];
    const float* scale = (const float*)d_in[1];
    const float* trans = (const float*)d_in[2];
    const float* ww    = (const float*)d_in[3];
    const float* bw    = (const float*)d_in[4];
    const float* gamma = (const float*)d_in[5];
    const float* beta  = (const float*)d_in[6];
    float* out = (float*)d_out;

    const int N = in_sizes[0] / D_DIM;       // 8192
    const int grid = (N + ROWS - 1) / ROWS;  // 256 -> 1 block/CU

    const size_t ws_needed = (size_t)O_DIM * (D_DIM / 2) * 2 * sizeof(float4); // 256 KB
    if (ws_size >= ws_needed) {
        wavekan_prep<<<(O_DIM * (D_DIM / 2) + 255) / 256, 256, 0, stream>>>(
            scale, trans, ww, bw, gamma, (float4*)d_ws);
        wavekan_main<true><<<grid, BLOCK, 0, stream>>>(
            x, scale, trans, ww, bw, gamma, beta, (const float4*)d_ws, out, N);
    } else {
        wavekan_main<false><<<grid, BLOCK, 0, stream>>>(
            x, scale, trans, ww, bw, gamma, beta, nullptr, out, N);
    }
}